// Round 2
// baseline (4080.147 us; speedup 1.0000x reference)
//
#include <hip/hip_runtime.h>
#include <cstdint>

// ---------------- workspace layout (bytes) ----------------
// Wt   : bf16 [2][4096][2048]  transposed weights (col-major rows of W)   32 MiB
// xbf  : bf16 [256][64][1024]  x converted to bf16                        32 MiB
// hbuf : bf16 [4][2][64][1024] ring buffer of h (slot = t & 3)             1 MiB
// kl   : double accumulator
// arr  : int [2][257] arrival counters
#define WS_WT   0UL
#define WS_XBF  33554432UL
#define WS_HBUF 67108864UL
#define WS_KL   68157440UL
#define WS_ARR  68157504UL

typedef __attribute__((ext_vector_type(8))) short short8;   // 8 x bf16 (4 VGPR)
typedef __attribute__((ext_vector_type(4))) float f32x4;    // MFMA acc

__device__ __forceinline__ unsigned short f2bf(float f) {
  unsigned int u = __float_as_uint(f);
  u += 0x7FFFu + ((u >> 16) & 1u);      // RNE
  return (unsigned short)(u >> 16);
}

__device__ __forceinline__ float sigm(float x) { return 1.0f / (1.0f + expf(-x)); }

// ---------------- threefry2x32 (matches jax._src.prng) ----------------
__device__ __forceinline__ void tf_round(uint32_t& x0, uint32_t& x1, int r) {
  x0 += x1; x1 = (x1 << r) | (x1 >> (32 - r)); x1 ^= x0;
}
__device__ __forceinline__ void threefry2x32_dev(uint32_t k0, uint32_t k1,
                                                 uint32_t c0, uint32_t c1,
                                                 uint32_t& o0, uint32_t& o1) {
  uint32_t ks2 = k0 ^ k1 ^ 0x1BD11BDAu;
  uint32_t x0 = c0 + k0, x1 = c1 + k1;
  tf_round(x0,x1,13); tf_round(x0,x1,15); tf_round(x0,x1,26); tf_round(x0,x1,6);
  x0 += k1;  x1 += ks2 + 1u;
  tf_round(x0,x1,17); tf_round(x0,x1,29); tf_round(x0,x1,16); tf_round(x0,x1,24);
  x0 += ks2; x1 += k0 + 2u;
  tf_round(x0,x1,13); tf_round(x0,x1,15); tf_round(x0,x1,26); tf_round(x0,x1,6);
  x0 += k0;  x1 += k1 + 3u;
  tf_round(x0,x1,17); tf_round(x0,x1,29); tf_round(x0,x1,16); tf_round(x0,x1,24);
  x0 += k1;  x1 += ks2 + 4u;
  tf_round(x0,x1,13); tf_round(x0,x1,15); tf_round(x0,x1,26); tf_round(x0,x1,6);
  x0 += ks2; x1 += k0 + 5u;
  o0 = x0; o1 = x1;
}

// XLA ErfInv32 (Giles polynomial, log1p form)
__device__ __forceinline__ float erfinv_f32(float x) {
  float w = -log1pf(-x * x);
  float p;
  if (w < 5.0f) {
    w -= 2.5f;
    p = 2.81022636e-08f;
    p = fmaf(p, w, 3.43273939e-07f);
    p = fmaf(p, w, -3.5233877e-06f);
    p = fmaf(p, w, -4.39150654e-06f);
    p = fmaf(p, w, 0.00021858087f);
    p = fmaf(p, w, -0.00125372503f);
    p = fmaf(p, w, -0.00417768164f);
    p = fmaf(p, w, 0.246640727f);
    p = fmaf(p, w, 1.50140941f);
  } else {
    w = sqrtf(w) - 3.0f;
    p = -0.000200214257f;
    p = fmaf(p, w, 0.000100950558f);
    p = fmaf(p, w, 0.00134934322f);
    p = fmaf(p, w, -0.00367342844f);
    p = fmaf(p, w, 0.00573950773f);
    p = fmaf(p, w, -0.0076224613f);
    p = fmaf(p, w, 0.00943887047f);
    p = fmaf(p, w, 1.00167406f);
    p = fmaf(p, w, 2.83297682f);
  }
  return p * x;
}

// bits -> N(0,1) exactly like jax.random.normal(float32)
__device__ __forceinline__ float bits_to_normal(uint32_t b) {
  float f = __uint_as_float((b >> 9) | 0x3f800000u) - 1.0f;   // [0,1)
  float u = fmaf(f, 2.0f, -0.99999994f);                      // *2 is exact
  u = fmaxf(-0.99999994f, u);
  return 1.41421356f * erfinv_f32(u);
}

// per-element KL contribution: log q(w|mu,sigma) - log p(w)
__device__ __forceinline__ double kl_elem(float w, float eps, float sigma) {
  float logq = -0.91893853320f - logf(sigma) - 0.5f * eps * eps;
  float t1 = w * 2.71828182846f;          // w / sigma1, sigma1 = e^-1
  float lp1 = -1.3052328943f - 0.5f * t1 * t1;   // -.5log2pi +1 +log(.25)
  float t2 = w * 1096.6331584f;           // w / sigma2, sigma2 = e^-7
  float lp2 = 5.7933793944f - 0.5f * t2 * t2;    // -.5log2pi +7 +log(.75)
  float mx = fmaxf(lp1, lp2);
  float logp = mx + log1pf(expf(fminf(lp1, lp2) - mx));
  return (double)logq - (double)logp;
}

// ---------------- kernel 1: sample weights + KL ----------------
// grid = 2 layers * 64 colblocks * 64 kblocks = 8192, block = 256
// thread (cc = tid>>2, kg = tid&3) handles col = cb*64+cc, k-pairs kb*16+kg*4+u
__global__ __launch_bounds__(256) void gen_weights(
    const float* __restrict__ mu, const float* __restrict__ rho,
    unsigned short* __restrict__ Wt, double* __restrict__ klsum,
    uint32_t ka0, uint32_t ka1, uint32_t kb0, uint32_t kb1)
{
  const int bid = blockIdx.x;
  const int l = bid >> 12;
  const int rem = bid & 4095;
  const int cb = rem >> 6, kb = rem & 63;
  const int tid = threadIdx.x;
  const int cc = tid >> 2, kg = tid & 3;
  const int col = cb * 64 + cc;
  const uint32_t K0 = l ? kb0 : ka0, K1 = l ? kb1 : ka1;
  const float* muL  = mu  + (size_t)l * 8388608;
  const float* rhoL = rho + (size_t)l * 8388608;
  const int kbase = kb * 16 + kg * 4;

  double kl = 0.0;
  unsigned short wlo[4], whi[4];
#pragma unroll
  for (int u = 0; u < 4; ++u) {
    const int kp = kbase + u;
    const uint32_t i = (uint32_t)(kp * 4096 + col);
    uint32_t r0, r1;
    threefry2x32_dev(K0, K1, i, i + 4194304u, r0, r1);
    // lower half (row = kp)
    {
      const float e = bits_to_normal(r0);
      const size_t off = (size_t)kp * 4096 + col;
      const float sg = log1pf(expf(rhoL[off])) + 1e-5f;
      const float w = fmaf(e, sg, muL[off]);
      kl += kl_elem(w, e, sg);
      wlo[u] = f2bf(w);
    }
    // upper half (row = kp + 1024)
    {
      const float e = bits_to_normal(r1);
      const size_t off = (size_t)(kp + 1024) * 4096 + col;
      const float sg = log1pf(expf(rhoL[off])) + 1e-5f;
      const float w = fmaf(e, sg, muL[off]);
      kl += kl_elem(w, e, sg);
      whi[u] = f2bf(w);
    }
  }
  const size_t wbase = ((size_t)(l * 4096 + col)) * 2048 + kbase;
  *(ushort4*)(Wt + wbase)        = make_ushort4(wlo[0], wlo[1], wlo[2], wlo[3]);
  *(ushort4*)(Wt + wbase + 1024) = make_ushort4(whi[0], whi[1], whi[2], whi[3]);

  // block KL reduction -> one double atomicAdd
#pragma unroll
  for (int off = 32; off > 0; off >>= 1) kl += __shfl_down(kl, off, 64);
  __shared__ double part[4];
  const int lane = tid & 63, wv = tid >> 6;
  if (lane == 0) part[wv] = kl;
  __syncthreads();
  if (tid == 0) atomicAdd(klsum, part[0] + part[1] + part[2] + part[3]);
}

// ---------------- kernel 2: convert x and h0 to bf16 ----------------
__global__ __launch_bounds__(256) void cvt_inputs(
    const float* __restrict__ x, const float* __restrict__ h0,
    unsigned short* __restrict__ xbf, unsigned short* __restrict__ hbuf)
{
  const int total = 4227072;   // (16777216 + 131072) / 4
  for (int idx = blockIdx.x * 256 + threadIdx.x; idx < total; idx += gridDim.x * 256) {
    if (idx < 4194304) {
      float4 v = ((const float4*)x)[idx];
      ((ushort4*)xbf)[idx] = make_ushort4(f2bf(v.x), f2bf(v.y), f2bf(v.z), f2bf(v.w));
    } else {
      const int j = idx - 4194304;
      float4 v = ((const float4*)h0)[j];
      ((ushort4*)hbuf)[j] = make_ushort4(f2bf(v.x), f2bf(v.y), f2bf(v.z), f2bf(v.w));
    }
  }
}

// ---------------- kernel 3: persistent LSTM recurrence ----------------
// 256 blocks (128/layer), 256 threads. Block owns 8 h-cols (32 gate cols).
// W slice [32 cols][2048 k] bf16 lives in 128 KiB LDS (XOR-swizzled).
// Wave w computes batch rows [16w,16w+16) with full K; c state in registers.
__global__ __launch_bounds__(256) void lstm_rec(
    const unsigned short* __restrict__ Wt, const unsigned short* __restrict__ xbf,
    unsigned short* __restrict__ hbuf, const float* __restrict__ c0,
    const float* __restrict__ bias, float* __restrict__ outp,
    int* __restrict__ arrive)
{
  extern __shared__ char lds[];
  const int tid = threadIdx.x;
  const int lane = tid & 63;
  const int wv = tid >> 6;
  const int blk = blockIdx.x;
  const int layer = blk >> 7;
  const int bi = blk & 127;
  const int hc0 = bi << 3;

  // ---- stage W slice -> LDS (once). gang g = wv in {i,j,f,o} ----
  {
    const int g = wv;
    const int c = lane >> 3;           // col within gang 0..7
    const int q = lane & 7;            // 16B chunk id
    const int cw = g * 8 + c;          // 0..31
    const unsigned short* src = Wt + (size_t)(layer * 4096 + g * 1024 + hc0 + c) * 2048;
    const int swz = (cw & 7) << 4;
    for (int it = 0; it < 32; ++it) {
      const int k = it * 64 + q * 8;
      short8 v = *(const short8*)(src + k);
      const int byte = (cw << 12) + k * 2;
      *(short8*)(lds + (byte ^ swz)) = v;
    }
  }
  __syncthreads();

  const int g4 = lane >> 4;            // 0..3
  const int c16 = lane & 15;
  const int myrow = wv * 16 + c16;     // batch row this lane feeds to MFMA A
  const int klane = g4 * 8;            // k offset within a 32-chunk
  const int cw0 = c16, cw1 = 16 + c16;
  const int bb0 = (cw0 << 12) + klane * 2, sz0 = (cw0 & 7) << 4;
  const int bb1 = (cw1 << 12) + klane * 2, sz1 = (cw1 & 7) << 4;

  const int hc = lane & 7;
  const bool act = (lane & 8) == 0;
  float cst[4];
  {
    const size_t base = (size_t)layer * 65536 + (size_t)(wv * 16 + g4 * 4) * 1024 + hc0 + hc;
#pragma unroll
    for (int r = 0; r < 4; ++r) cst[r] = act ? c0[base + r * 1024] : 0.0f;
  }
  float bi_i = 0, bi_j = 0, bi_f = 0, bi_o = 0;
  if (act) {
    bi_i = bias[layer * 4096 + hc0 + hc];
    bi_j = bias[layer * 4096 + 1024 + hc0 + hc];
    bi_f = bias[layer * 4096 + 2048 + hc0 + hc];
    bi_o = bias[layer * 4096 + 3072 + hc0 + hc];
  }
  int* arr = arrive + layer * 257;

  for (int t = 0; t < 256; ++t) {
    f32x4 a0 = {0.f, 0.f, 0.f, 0.f}, a1 = {0.f, 0.f, 0.f, 0.f};
    // ---- x half (K 0..1023), independent of h_t ----
    const unsigned short* xa = xbf + (size_t)(t * 64 + myrow) * 1024 + klane;
#pragma unroll 4
    for (int kk = 0; kk < 32; ++kk) {
      short8 av = *(const short8*)(xa + kk * 32);
      short8 b0 = *(const short8*)(lds + ((bb0 + kk * 64) ^ sz0));
      short8 b1 = *(const short8*)(lds + ((bb1 + kk * 64) ^ sz1));
      a0 = __builtin_amdgcn_mfma_f32_16x16x32_bf16(av, b0, a0, 0, 0, 0);
      a1 = __builtin_amdgcn_mfma_f32_16x16x32_bf16(av, b1, a1, 0, 0, 0);
    }
    // ---- wait for h_t fully published ----
    if (t > 0) {
      if (tid == 0) {
        while (__hip_atomic_load(arr + t, __ATOMIC_RELAXED, __HIP_MEMORY_SCOPE_AGENT) < 128)
          __builtin_amdgcn_s_sleep(1);
        __builtin_amdgcn_fence(__ATOMIC_ACQUIRE, "agent");
      }
      __syncthreads();
    }
    // ---- h half (K 1024..2047) ----
    const unsigned short* ha = hbuf + (size_t)(((t & 3) * 2 + layer) * 64 + myrow) * 1024 + klane;
#pragma unroll 4
    for (int kk = 0; kk < 32; ++kk) {
      short8 av = *(const short8*)(ha + kk * 32);
      const int kb2 = (32 + kk) * 64;
      short8 b0 = *(const short8*)(lds + ((bb0 + kb2) ^ sz0));
      short8 b1 = *(const short8*)(lds + ((bb1 + kb2) ^ sz1));
      a0 = __builtin_amdgcn_mfma_f32_16x16x32_bf16(av, b0, a0, 0, 0, 0);
      a1 = __builtin_amdgcn_mfma_f32_16x16x32_bf16(av, b1, a1, 0, 0, 0);
    }
    // ---- epilogue: pair i/j and f/o via shfl_xor(8), update c,h ----
    float pj[4], po[4];
#pragma unroll
    for (int r = 0; r < 4; ++r) {
      pj[r] = __shfl_xor(a0[r], 8, 64);
      po[r] = __shfl_xor(a1[r], 8, 64);
    }
    if (act) {
      const int slotw = (t + 1) & 3;
      unsigned short* hw = hbuf + (size_t)((slotw * 2 + layer) * 64) * 1024;
      float* op = outp + (size_t)t * 65536;
#pragma unroll
      for (int r = 0; r < 4; ++r) {
        const float iv = a0[r] + bi_i, jv = pj[r] + bi_j;
        const float fv = a1[r] + bi_f, ov = po[r] + bi_o;
        const float nc = cst[r] * sigm(fv + 1.0f) + sigm(iv) * tanhf(jv);
        const float nh = tanhf(nc) * sigm(ov);
        cst[r] = nc;
        const int b = wv * 16 + g4 * 4 + r;
        hw[(size_t)b * 1024 + hc0 + hc] = f2bf(nh);
        if (layer == 1) op[(size_t)b * 1024 + hc0 + hc] = nh;
        if (t == 255) {
          outp[16777216 + (size_t)layer * 65536 + (size_t)b * 1024 + hc0 + hc] = nh;
          outp[16908288 + (size_t)layer * 65536 + (size_t)b * 1024 + hc0 + hc] = nc;
        }
      }
    }
    __syncthreads();   // drains all waves' stores to L2 before publish
    if (tid == 0)
      __hip_atomic_fetch_add(arr + t + 1, 1, __ATOMIC_RELEASE, __HIP_MEMORY_SCOPE_AGENT);
  }
}

__global__ void finalize_kl(const double* __restrict__ klsum, float* __restrict__ outp) {
  outp[17039360] = (float)(*klsum);
}

// ---------------- host ----------------
static void host_threefry(uint32_t k0, uint32_t k1, uint32_t c0, uint32_t c1,
                          uint32_t& o0, uint32_t& o1) {
  auto rot = [](uint32_t x, int r) { return (x << r) | (x >> (32 - r)); };
  const int ra[4] = {13, 15, 26, 6}, rb[4] = {17, 29, 16, 24};
  uint32_t ks2 = k0 ^ k1 ^ 0x1BD11BDAu, x0 = c0 + k0, x1 = c1 + k1;
  for (int i = 0; i < 4; ++i) { x0 += x1; x1 = rot(x1, ra[i]); x1 ^= x0; } x0 += k1;  x1 += ks2 + 1u;
  for (int i = 0; i < 4; ++i) { x0 += x1; x1 = rot(x1, rb[i]); x1 ^= x0; } x0 += ks2; x1 += k0 + 2u;
  for (int i = 0; i < 4; ++i) { x0 += x1; x1 = rot(x1, ra[i]); x1 ^= x0; } x0 += k0;  x1 += k1 + 3u;
  for (int i = 0; i < 4; ++i) { x0 += x1; x1 = rot(x1, rb[i]); x1 ^= x0; } x0 += k1;  x1 += ks2 + 4u;
  for (int i = 0; i < 4; ++i) { x0 += x1; x1 = rot(x1, ra[i]); x1 ^= x0; } x0 += ks2; x1 += k0 + 5u;
  o0 = x0; o1 = x1;
}

extern "C" void kernel_launch(void* const* d_in, const int* in_sizes, int n_in,
                              void* d_out, int out_size, void* d_ws, size_t ws_size,
                              hipStream_t stream) {
  const float* x    = (const float*)d_in[0];
  const float* h0   = (const float*)d_in[1];
  const float* c0   = (const float*)d_in[2];
  const float* mu   = (const float*)d_in[3];
  const float* rho  = (const float*)d_in[4];
  const float* bias = (const float*)d_in[5];
  float* outp = (float*)d_out;
  char* ws = (char*)d_ws;

  unsigned short* Wt   = (unsigned short*)(ws + WS_WT);
  unsigned short* xbf  = (unsigned short*)(ws + WS_XBF);
  unsigned short* hbuf = (unsigned short*)(ws + WS_HBUF);
  double* klsum        = (double*)(ws + WS_KL);
  int* arrive          = (int*)(ws + WS_ARR);

  // zero kl accumulator + arrival counters
  hipMemsetAsync(ws + WS_KL, 0, 4096, stream);

  // folded per-layer threefry keys: fold_in(key(1), l) = threefry((0,1),(0,l))
  uint32_t ka0, ka1, kb0, kb1;
  host_threefry(0u, 1u, 0u, 0u, ka0, ka1);
  host_threefry(0u, 1u, 0u, 1u, kb0, kb1);

  gen_weights<<<8192, 256, 0, stream>>>(mu, rho, Wt, klsum, ka0, ka1, kb0, kb1);
  cvt_inputs<<<8192, 256, 0, stream>>>(x, h0, xbf, hbuf);

  hipFuncSetAttribute((const void*)lstm_rec,
                      hipFuncAttributeMaxDynamicSharedMemorySize, 131072);
  lstm_rec<<<256, 256, 131072, stream>>>(Wt, xbf, hbuf, c0, bias, outp, arrive);
  finalize_kl<<<1, 1, 0, stream>>>(klsum, outp);
}